// Round 3
// baseline (31454.144 us; speedup 1.0000x reference)
//
#include <hip/hip_runtime.h>
#include <hip/hip_bf16.h>
#include <math.h>

#define H 1024
#define V 32000
#define B 64
#define S 64
#define T 13

typedef __bf16 bf16x8 __attribute__((ext_vector_type(8)));
typedef float f32x4 __attribute__((ext_vector_type(4)));

__device__ __forceinline__ float sigmoidf_fast(float x) { return 1.0f / (1.0f + __expf(-x)); }
__device__ __forceinline__ float tanhf_fast(float x) { return 1.0f - 2.0f / (1.0f + __expf(2.0f * x)); }

// Swizzled (fragment-major) element offset within one 64-row m-block:
// chunk layout: [ks][mt][lane] * 8 elems;  m = mt*16+(lane&15), k = ks*32+(lane>>4)*8+j
__device__ __forceinline__ size_t swz_off(int m, int k) {
    return ((size_t)(k >> 5) * 2048) + (size_t)((m >> 4) & 3) * 512 +
           (size_t)((m & 15) | (((k >> 3) & 3) << 4)) * 8 + (k & 7);
}

__device__ __forceinline__ bf16x8 cvt8(float4 lo, float4 hi) {
    bf16x8 v;
    v[0] = (__bf16)lo.x; v[1] = (__bf16)lo.y; v[2] = (__bf16)lo.z; v[3] = (__bf16)lo.w;
    v[4] = (__bf16)hi.x; v[5] = (__bf16)hi.y; v[6] = (__bf16)hi.z; v[7] = (__bf16)hi.w;
    return v;
}

// ---- one-time weight conversion: row-major f32 [N][Ktot] -> fragment-major bf16 ----
// For concatenated weights (gates): k < K1 reads W1 (ld K1), else W2 (ld Ktot-K1).
__global__ void conv_w(const float* __restrict__ W1, const float* __restrict__ W2,
                       int K1, int Ktot, int total_chunks, __bf16* __restrict__ dst) {
    int c = blockIdx.x * 256 + threadIdx.x;
    if (c >= total_chunks) return;
    int Kd32 = Ktot >> 5;
    int cpt = Kd32 << 6;
    int nt = c / cpt, rem = c - nt * cpt;
    int ks = rem >> 6, lane = rem & 63;
    int n = nt * 16 + (lane & 15);
    int k = ks * 32 + ((lane >> 4) << 3);
    const float* src = (k < K1) ? (W1 + (size_t)n * K1 + k)
                                : (W2 + (size_t)n * (Ktot - K1) + (k - K1));
    *(bf16x8*)(dst + (size_t)c * 8) = cvt8(*(const float4*)src, *(const float4*)(src + 4));
}

// ---- one-time activation conversion (enc_out) -> swizzled bf16 A (M=4096) ----
__global__ void conv_a(const float* __restrict__ A, int Kd32, int total_chunks,
                       __bf16* __restrict__ dst) {
    int c = blockIdx.x * 256 + threadIdx.x;
    if (c >= total_chunks) return;
    int cpm = Kd32 << 8;                 // chunks per 64-row m-block
    int mb = c / cpm, rem = c - mb * cpm;
    int ks = rem >> 8, rem2 = rem & 255;
    int mt = rem2 >> 6, lane = rem2 & 63;
    int m = mb * 64 + mt * 16 + (lane & 15);
    int k = ks * 32 + ((lane >> 4) << 3);
    const float* src = A + (size_t)m * (Kd32 * 32) + k;
    *(bf16x8*)(dst + (size_t)c * 8) = cvt8(*(const float4*)src, *(const float4*)(src + 4));
}

// ---- MFMA GEMM on fragment-major operands, no LDS ----
// A: swizzled bf16 (blockIdx.y selects 64-row m-block), W: swizzled bf16.
// grid (N/64, Mblocks, SK). SK>1: C += z*64*ldc (partials, bias must be null).
__global__ __launch_bounds__(256) void gemm_frag(
    const __bf16* __restrict__ Asw, const __bf16* __restrict__ Wsw,
    const float* __restrict__ bias, float* __restrict__ C, int ldc,
    int Kd32, int ks_per_z) {
    const int lane = threadIdx.x & 63, wv = threadIdx.x >> 6;
    const int nt = blockIdx.x * 4 + wv;
    const int ks0 = blockIdx.z * ks_per_z, ks1 = ks0 + ks_per_z;
    const __bf16* Ab = Asw + (size_t)blockIdx.y * Kd32 * 2048 + (size_t)lane * 8;
    const __bf16* Wb = Wsw + (size_t)nt * Kd32 * 512 + (size_t)lane * 8;
    C += (size_t)(blockIdx.y + blockIdx.z) * 64 * ldc;

    f32x4 acc[4];
#pragma unroll
    for (int i = 0; i < 4; ++i) acc[i] = (f32x4){0.f, 0.f, 0.f, 0.f};

    bf16x8 aB[2][4], bB[2];
    auto LD = [&](int ks, int s) {
        bB[s] = *(const bf16x8*)(Wb + (size_t)ks * 512);
#pragma unroll
        for (int i = 0; i < 4; ++i)
            aB[s][i] = *(const bf16x8*)(Ab + (size_t)ks * 2048 + i * 512);
    };
    LD(ks0, 0);
    if (ks0 + 1 < ks1) LD(ks0 + 1, 1);
    for (int ks = ks0; ks < ks1; ++ks) {
        int s = (ks - ks0) & 1;
#pragma unroll
        for (int i = 0; i < 4; ++i)
            acc[i] = __builtin_amdgcn_mfma_f32_16x16x32_bf16(aB[s][i], bB[s], acc[i], 0, 0, 0);
        if (ks + 2 < ks1) LD(ks + 2, s);
    }

    const int n = nt * 16 + (lane & 15);
    const int rbase = (lane >> 4) * 4;
    const float bv = bias ? bias[n] : 0.f;
#pragma unroll
    for (int i = 0; i < 4; ++i)
#pragma unroll
        for (int r = 0; r < 4; ++r)
            C[(size_t)(i * 16 + rbase + r) * ldc + n] = acc[i][r] + bv;
}

// ---- attention (+ fused embedding gather + q partial reduction) ----
// One block per batch row. q = ba + sum_z qpart[z]; scores = Va.tanh(q+keys);
// softmax; ctx -> swizzled bf16 into gatesA ctx region; x -> gatesA x region.
__global__ __launch_bounds__(256) void attn_ctx(
    const float* __restrict__ qpart, const float* __restrict__ ba,
    const float* __restrict__ keys, const float* __restrict__ enc_out,
    const float* __restrict__ Va, const int* __restrict__ target,
    const float* __restrict__ emb, __bf16* __restrict__ gatesA,
    float* __restrict__ attn_out, int t) {
    const int b = blockIdx.x, tid = threadIdx.x;
    // fused embed: threads 0..127 write the x region (k in [0,1024))
    if (tid < 128) {
        const int tok = (t == 0) ? 2 : target[b * T + t - 1];
        const float* src = emb + (size_t)tok * H + tid * 8;
        bf16x8 v = cvt8(*(const float4*)src, *(const float4*)(src + 4));
        int ks = tid >> 2, lh = tid & 3;
        size_t off = ((size_t)ks * 2048) + (size_t)((b >> 4) & 3) * 512 +
                     (size_t)((b & 15) | (lh << 4)) * 8;
        *(bf16x8*)(gatesA + off) = v;
    }
    __shared__ float qs[H];
    __shared__ float vas[H];
    __shared__ float sw[S];
    {
        int i = tid;  // H/4 == 256 float4 groups
        float4 s = ((const float4*)ba)[i];
#pragma unroll
        for (int z = 0; z < 8; ++z) {
            float4 p = ((const float4*)(qpart + (size_t)z * B * H + (size_t)b * H))[i];
            s.x += p.x; s.y += p.y; s.z += p.z; s.w += p.w;
        }
        ((float4*)qs)[i] = s;
        ((float4*)vas)[i] = ((const float4*)Va)[i];
    }
    __syncthreads();
    const int s = tid >> 2, hq = tid & 3;
    const float* kp = keys + ((size_t)b * S + s) * H;
    float part = 0.f;
    for (int j = 0; j < H / 4; ++j) {
        int hh = j * 4 + hq;
        part += vas[hh] * tanhf_fast(qs[hh] + kp[hh]);
    }
    part += __shfl_xor(part, 1);
    part += __shfl_xor(part, 2);
    if (hq == 0) sw[s] = part;
    __syncthreads();
    if (tid < 64) {
        float v = sw[tid];
        float m = v;
#pragma unroll
        for (int o = 32; o; o >>= 1) m = fmaxf(m, __shfl_xor(m, o));
        float e = __expf(v - m);
        float ssum = e;
#pragma unroll
        for (int o = 32; o; o >>= 1) ssum += __shfl_xor(ssum, o);
        float w = e / ssum;
        sw[tid] = w;
        attn_out[((size_t)b * T + t) * S + tid] = w;
    }
    __syncthreads();
    const float* Eb = enc_out + (size_t)b * S * H;
    float a0 = 0.f, a1 = 0.f, a2 = 0.f, a3 = 0.f;
    for (int s2 = 0; s2 < S; ++s2) {
        float w = sw[s2];
        const float* row = Eb + (size_t)s2 * H;
        a0 += w * row[tid];
        a1 += w * row[tid + 256];
        a2 += w * row[tid + 512];
        a3 += w * row[tid + 768];
    }
    __bf16* ctxb = gatesA + 65536;  // ctx region: k in [1024,2048)
    ctxb[swz_off(b, tid)]       = (__bf16)a0;
    ctxb[swz_off(b, tid + 256)] = (__bf16)a1;
    ctxb[swz_off(b, tid + 512)] = (__bf16)a2;
    ctxb[swz_off(b, tid + 768)] = (__bf16)a3;
}

// ---- LSTM cell (sums 4 gate partials + biases) + LayerNorm; writes f32 h,c,
// swizzled bf16 h (gatesA h region) and swizzled bf16 nh ----
__global__ __launch_bounds__(256) void cell_ln(
    const float* __restrict__ gpart, const float* __restrict__ b_ih,
    const float* __restrict__ b_hh, float* __restrict__ h, float* __restrict__ cst,
    __bf16* __restrict__ hswz, __bf16* __restrict__ nhs,
    const float* __restrict__ ln_g, const float* __restrict__ ln_b) {
    const int b = blockIdx.x, tid = threadIdx.x;
    float* cb = cst + (size_t)b * H;
    float* hb = h + (size_t)b * H;
    float hv[4];
    float sum = 0.f, sumsq = 0.f;
#pragma unroll
    for (int j = 0; j < 4; ++j) {
        int n = tid + j * 256;
        float gi = b_ih[n] + b_hh[n];
        float gf = b_ih[n + H] + b_hh[n + H];
        float gg = b_ih[n + 2 * H] + b_hh[n + 2 * H];
        float go = b_ih[n + 3 * H] + b_hh[n + 3 * H];
#pragma unroll
        for (int z = 0; z < 4; ++z) {
            const float* gp = gpart + (size_t)z * B * 4 * H + (size_t)b * 4 * H;
            gi += gp[n]; gf += gp[n + H]; gg += gp[n + 2 * H]; go += gp[n + 3 * H];
        }
        float ig = sigmoidf_fast(gi);
        float fg = sigmoidf_fast(gf);
        float gg2 = tanhf_fast(gg);
        float og = sigmoidf_fast(go);
        float cv = fg * cb[n] + ig * gg2;
        cb[n] = cv;
        float hn = og * tanhf_fast(cv);
        hb[n] = hn;
        hswz[swz_off(b, n)] = (__bf16)hn;
        hv[j] = hn;
        sum += hn;
        sumsq += hn * hn;
    }
#pragma unroll
    for (int o = 32; o; o >>= 1) { sum += __shfl_xor(sum, o); sumsq += __shfl_xor(sumsq, o); }
    __shared__ float rs[4], rq[4];
    if ((tid & 63) == 0) { rs[tid >> 6] = sum; rq[tid >> 6] = sumsq; }
    __syncthreads();
    sum = rs[0] + rs[1] + rs[2] + rs[3];
    sumsq = rq[0] + rq[1] + rq[2] + rq[3];
    float mu = sum * (1.f / H);
    float var = sumsq * (1.f / H) - mu * mu;
    float inv = rsqrtf(var + 1e-5f);
#pragma unroll
    for (int j = 0; j < 4; ++j) {
        int n = tid + j * 256;
        nhs[swz_off(b, n)] = (__bf16)((hv[j] - mu) * inv * ln_g[n] + ln_b[n]);
    }
}

// ---- in-place log-softmax over V for row (b,t) ----
__global__ void logsoftmax_inplace(float* __restrict__ out, int t) {
    const int b = blockIdx.x, tid = threadIdx.x;
    float* row = out + ((size_t)b * T + t) * V;
    float m = -3.4e38f;
    for (int v = tid; v < V; v += 1024) m = fmaxf(m, row[v]);
#pragma unroll
    for (int o = 32; o; o >>= 1) m = fmaxf(m, __shfl_xor(m, o));
    __shared__ float red[16];
    if ((tid & 63) == 0) red[tid >> 6] = m;
    __syncthreads();
    if (tid < 16) {
        float mm = red[tid];
#pragma unroll
        for (int o = 8; o; o >>= 1) mm = fmaxf(mm, __shfl_xor(mm, o));
        red[tid] = mm;
    }
    __syncthreads();
    m = red[0];
    float ssum = 0.f;
    for (int v = tid; v < V; v += 1024) ssum += __expf(row[v] - m);
#pragma unroll
    for (int o = 32; o; o >>= 1) ssum += __shfl_xor(ssum, o);
    __shared__ float red2[16];
    if ((tid & 63) == 0) red2[tid >> 6] = ssum;
    __syncthreads();
    if (tid < 16) {
        float s2 = red2[tid];
#pragma unroll
        for (int o = 8; o; o >>= 1) s2 += __shfl_xor(s2, o);
        red2[tid] = s2;
    }
    __syncthreads();
    float L = m + logf(red2[0]);
    for (int v = tid; v < V; v += 1024) row[v] -= L;
}

// ---- init h,c f32 from enc_h/enc_c and swizzled bf16 h ----
__global__ void init_state(const float* __restrict__ eh, const float* __restrict__ ec,
                           float* __restrict__ h, float* __restrict__ cst,
                           __bf16* __restrict__ hswz) {
    const int b = blockIdx.x, tid = threadIdx.x;
#pragma unroll
    for (int j = 0; j < 4; ++j) {
        int n = tid + j * 256;
        float v = eh[(size_t)b * H + n];
        h[(size_t)b * H + n] = v;
        hswz[swz_off(b, n)] = (__bf16)v;
        cst[(size_t)b * H + n] = ec[(size_t)b * H + n];
    }
}

__global__ void copy2(const float* __restrict__ a, const float* __restrict__ bsrc,
                      float* __restrict__ x, float* __restrict__ y) {
    size_t i = (size_t)blockIdx.x * 256 + threadIdx.x;
    ((float4*)x)[i] = ((const float4*)a)[i];
    ((float4*)y)[i] = ((const float4*)bsrc)[i];
}

extern "C" void kernel_launch(void* const* d_in, const int* in_sizes, int n_in,
                              void* d_out, int out_size, void* d_ws, size_t ws_size,
                              hipStream_t stream) {
    const float* enc_out = (const float*)d_in[0];
    const float* enc_h   = (const float*)d_in[1];
    const float* enc_c   = (const float*)d_in[2];
    const int*   target  = (const int*)d_in[3];
    const float* emb     = (const float*)d_in[4];
    const float* Wa      = (const float*)d_in[5];
    const float* ba      = (const float*)d_in[6];
    const float* Ua      = (const float*)d_in[7];
    const float* bu      = (const float*)d_in[8];
    const float* Va      = (const float*)d_in[9];
    // d_in[10] = bv: constant score offset, cancels in softmax; omitted.
    const float* W_ih    = (const float*)d_in[11];
    const float* W_hh    = (const float*)d_in[12];
    const float* b_ih    = (const float*)d_in[13];
    const float* b_hh    = (const float*)d_in[14];
    const float* ln_g    = (const float*)d_in[15];
    const float* ln_b    = (const float*)d_in[16];
    const float* outW    = (const float*)d_in[17];
    const float* outb    = (const float*)d_in[18];
    float* out = (float*)d_out;

    // ---- workspace layout ----
    __bf16* outW_s = (__bf16*)d_ws;                    // 2000*32*512   = 32,768,000
    __bf16* Wcat_s = outW_s + 32768000;                // 256*96*512    = 12,582,912
    __bf16* Ua_s   = Wcat_s + 12582912;                // 64*32*512     =  1,048,576
    __bf16* Wa_s   = Ua_s   + 1048576;                 //                  1,048,576
    __bf16* enc_s  = Wa_s   + 1048576;                 // 64*32*2048    =  4,194,304
    __bf16* gatesA = enc_s  + 4194304;                 // 96*2048       =    196,608
    __bf16* nhs    = gatesA + 196608;                  // 32*2048       =     65,536
    float*  fbase  = (float*)(nhs + 65536);
    float*  keys   = fbase;                            // 4096*1024
    float*  qpart  = keys  + 4194304;                  // 8*64*1024
    float*  gpart  = qpart + 524288;                   // 4*64*4096
    float*  h      = gpart + 1048576;                  // 64*1024
    float*  c      = h + 65536;                        // 64*1024
    __bf16* hswz   = gatesA + 131072;                  // h region of gatesA (k in [2048,3072))

    const size_t HOFF = (size_t)B * T * V;
    const size_t COFF = HOFF + (size_t)B * H;
    const size_t AOFF = COFF + (size_t)B * H;

    // ---- one-time conversions ----
    hipLaunchKernelGGL(conv_w, dim3(16000), dim3(256), 0, stream,
                       outW, outW, H, H, 4096000, outW_s);
    hipLaunchKernelGGL(conv_w, dim3(6144), dim3(256), 0, stream,
                       W_ih, W_hh, 2 * H, 3 * H, 1572864, Wcat_s);
    hipLaunchKernelGGL(conv_w, dim3(512), dim3(256), 0, stream,
                       Ua, Ua, H, H, 131072, Ua_s);
    hipLaunchKernelGGL(conv_w, dim3(512), dim3(256), 0, stream,
                       Wa, Wa, H, H, 131072, Wa_s);
    hipLaunchKernelGGL(conv_a, dim3(2048), dim3(256), 0, stream,
                       enc_out, 32, 524288, enc_s);
    hipLaunchKernelGGL(init_state, dim3(B), dim3(256), 0, stream, enc_h, enc_c, h, c, hswz);
    // keys_proj = enc_out @ Ua^T + bu : grid (1024/64, 4096/64, 1)
    hipLaunchKernelGGL(gemm_frag, dim3(16, 64, 1), dim3(256), 0, stream,
                       enc_s, Ua_s, bu, keys, H, 32, 32);

    for (int t = 0; t < T; ++t) {
        // q partials = h @ Wa^T  (SK=8 -> 128 blocks)
        hipLaunchKernelGGL(gemm_frag, dim3(16, 1, 8), dim3(256), 0, stream,
                           hswz, Wa_s, nullptr, qpart, H, 32, 4);
        hipLaunchKernelGGL(attn_ctx, dim3(B), dim3(256), 0, stream,
                           qpart, ba, keys, enc_out, Va, target, emb, gatesA,
                           out + AOFF, t);
        // gate partials = [x|ctx|h] @ [W_ih|W_hh]^T  (SK=4 -> 256 blocks)
        hipLaunchKernelGGL(gemm_frag, dim3(64, 1, 4), dim3(256), 0, stream,
                           gatesA, Wcat_s, nullptr, gpart, 4 * H, 96, 24);
        hipLaunchKernelGGL(cell_ln, dim3(B), dim3(256), 0, stream,
                           gpart, b_ih, b_hh, h, c, hswz, nhs, ln_g, ln_b);
        // logits into logp slot (row stride T*V)
        hipLaunchKernelGGL(gemm_frag, dim3(500, 1, 1), dim3(256), 0, stream,
                           nhs, outW_s, outb, out + (size_t)t * V, T * V, 32, 32);
        hipLaunchKernelGGL(logsoftmax_inplace, dim3(B), dim3(1024), 0, stream, out, t);
    }
    hipLaunchKernelGGL(copy2, dim3(64), dim3(256), 0, stream, h, c, out + HOFF, out + COFF);
}